// Round 1
// baseline (132.646 us; speedup 1.0000x reference)
//
#include <hip/hip_runtime.h>
#include <hip/hip_bf16.h>

#define D 128
#define NOPS 4
#define BS_STRIDE 136  // padded bf16 row stride: 272 B = 16B-aligned, 2-way bank alias (free)
#define NSLAB 2        // 64-row slabs per block; grid 1024 = exactly 4 blocks/CU (LDS limit)

typedef __attribute__((ext_vector_type(8))) short short8;
typedef __attribute__((ext_vector_type(4))) float float4_t;

// ---------------------------------------------------------------------------
// Kernel 1: fold the 4 candidate ops into one combined matrix/bias.
//   Wc[f][d] = sum_o weights[o] * W[o][f][d]   (stored bf16)
//   bc[f]    = sum_o weights[o] * b[o][f]      (stored fp32)
// ---------------------------------------------------------------------------
__global__ void combine_kernel(const float* __restrict__ W,
                               const float* __restrict__ b,
                               const float* __restrict__ wts,
                               __hip_bfloat16* __restrict__ Wc,
                               float* __restrict__ bc) {
    int idx = blockIdx.x * blockDim.x + threadIdx.x;
    float w0 = wts[0], w1 = wts[1], w2 = wts[2], w3 = wts[3];
    if (idx < D * D) {
        float v = w0 * W[idx] + w1 * W[D * D + idx]
                + w2 * W[2 * D * D + idx] + w3 * W[3 * D * D + idx];
        Wc[idx] = __float2bfloat16(v);
    }
    if (idx < D) {
        bc[idx] = w0 * b[idx] + w1 * b[D + idx] + w2 * b[2 * D + idx] + w3 * b[3 * D + idx];
    }
}

// ---------------------------------------------------------------------------
// Kernel 2: y[m][f] = sum_d x[m][d] * Wc[f][d] + bc[f]
// M = B*S = 131072 rows. 256 threads = 4 waves/block; each wave does a
// 16-row x 128-col slab via mfma_f32_16x16x32_bf16.
//
// OPERAND SWAP vs previous version: A-frag = Wc (from LDS), B-frag = x.
// Output tile is then D[f][m] with f = quad*4+r per lane -> each lane holds
// 4 CONSECUTIVE y columns -> one dwordx4 store (was 32 scalar dword stores).
// Each block processes NSLAB slabs so the 32 KiB Wc LDS staging + barrier is
// amortized 2x (grid 1024 = exactly resident, one pass, no tail).
// ---------------------------------------------------------------------------
__device__ inline short8 cvt8_bf16(float4_t a, float4_t b) {
    union { short8 s; __hip_bfloat16 h[8]; } u;
    u.h[0] = __float2bfloat16(a[0]);
    u.h[1] = __float2bfloat16(a[1]);
    u.h[2] = __float2bfloat16(a[2]);
    u.h[3] = __float2bfloat16(a[3]);
    u.h[4] = __float2bfloat16(b[0]);
    u.h[5] = __float2bfloat16(b[1]);
    u.h[6] = __float2bfloat16(b[2]);
    u.h[7] = __float2bfloat16(b[3]);
    return u.s;
}

__global__ __launch_bounds__(256, 4) void gemm_kernel(const float* __restrict__ x,
                                                      const __hip_bfloat16* __restrict__ Wc,
                                                      const float* __restrict__ bc,
                                                      float* __restrict__ y,
                                                      int M) {
    __shared__ __align__(16) __hip_bfloat16 Bs[D * BS_STRIDE];  // 34816 B -> 4 blocks/CU

    const int tid  = threadIdx.x;
    const int lane = tid & 63;
    const int wave = tid >> 6;

    // ---- stage Wc -> LDS (2048 chunks of 8 bf16; coalesced 16B loads) ----
    #pragma unroll
    for (int i = 0; i < 8; i++) {
        int c  = i * 256 + tid;      // 0..2047
        int n  = c >> 4;             // row (0..127)
        int ko = (c & 15) << 3;      // k offset (0,8,...,120)
        short8 v = *(const short8*)((const short*)Wc + n * D + ko);
        *(short8*)((short*)Bs + n * BS_STRIDE + ko) = v;
    }

    const int row  = lane & 15;   // A: f within tile / B: m within tile / C: col (= m)
    const int quad = lane >> 4;

    // bias for f = ft*16 + quad*4 + r  (preload before barrier; 8 x float4)
    float4_t bias[8];
    #pragma unroll
    for (int ft = 0; ft < 8; ft++)
        bias[ft] = *(const float4_t*)(bc + ft * 16 + quad * 4);

    __syncthreads();

    if (blockIdx.x * (64 * NSLAB) >= M) return;
    const int mbase = blockIdx.x * (64 * NSLAB) + wave * 16 + row;

    #pragma unroll
    for (int s = 0; s < NSLAB; s++) {
        const int m = mbase + s * 64;  // this lane's x/y row

        // ---- batch all x loads for the slab (8 x dwordx4, nontemporal) ----
        const float* xp = x + (size_t)m * D + quad * 8;
        short8 xf[4];
        #pragma unroll
        for (int ks = 0; ks < 4; ks++) {
            float4_t a0 = __builtin_nontemporal_load((const float4_t*)(xp + ks * 32));
            float4_t a1 = __builtin_nontemporal_load((const float4_t*)(xp + ks * 32 + 4));
            xf[ks] = cvt8_bf16(a0, a1);
        }

        float4_t acc[8];
        #pragma unroll
        for (int i = 0; i < 8; i++) acc[i] = (float4_t)(0.f);

        // ---- MFMA: A = Wc[f][k] (LDS), B = x^T[k][m] -> D[f][m] ----
        #pragma unroll
        for (int ks = 0; ks < 4; ks++) {
            const short* bp = (const short*)Bs + ks * 32 + quad * 8;
            #pragma unroll
            for (int ft = 0; ft < 8; ft++) {
                // A frag: Wc[f = ft*16 + row][k = ks*32 + quad*8 + j]
                short8 wfrag = *(const short8*)(bp + (ft * 16 + row) * BS_STRIDE);
                acc[ft] = __builtin_amdgcn_mfma_f32_16x16x32_bf16(wfrag, xf[ks], acc[ft], 0, 0, 0);
            }
        }

        // ---- epilogue: lane holds y[m][ft*16 + quad*4 .. +3] -> dwordx4 ----
        float* yp = y + (size_t)m * D + quad * 4;
        #pragma unroll
        for (int ft = 0; ft < 8; ft++) {
            float4_t out;
            out[0] = acc[ft][0] + bias[ft][0];
            out[1] = acc[ft][1] + bias[ft][1];
            out[2] = acc[ft][2] + bias[ft][2];
            out[3] = acc[ft][3] + bias[ft][3];
            __builtin_nontemporal_store(out, (float4_t*)(yp + ft * 16));
        }
    }
}

extern "C" void kernel_launch(void* const* d_in, const int* in_sizes, int n_in,
                              void* d_out, int out_size, void* d_ws, size_t ws_size,
                              hipStream_t stream) {
    const float* x   = (const float*)d_in[0];   // (B,S,D) fp32
    const float* W   = (const float*)d_in[1];   // (NOPS,D,D) fp32
    const float* b   = (const float*)d_in[2];   // (NOPS,D) fp32
    const float* wts = (const float*)d_in[3];   // (NOPS,) fp32
    float* y = (float*)d_out;

    __hip_bfloat16* Wc = (__hip_bfloat16*)d_ws;
    float* bc = (float*)((char*)d_ws + D * D * sizeof(__hip_bfloat16));

    combine_kernel<<<(D * D + 255) / 256, 256, 0, stream>>>(W, b, wts, Wc, bc);

    const int M = in_sizes[0] / D;  // B*S = 131072
    gemm_kernel<<<M / (64 * NSLAB), 256, 0, stream>>>(x, Wc, bc, y, M);
}

// Round 2
// 128.026 us; speedup vs baseline: 1.0361x; 1.0361x over previous
//
#include <hip/hip_runtime.h>
#include <hip/hip_bf16.h>

#define D 128
#define NOPS 4
#define BS_STRIDE 136   // padded bf16 row stride: 272 B -> 2-way bank alias (free)
#define ROWS_PER_BLOCK 128  // 2 slabs x 64 rows (4 row-slab waves x 16 rows)

typedef __attribute__((ext_vector_type(8))) short short8;
typedef __attribute__((ext_vector_type(4))) float float4_t;

// ---------------------------------------------------------------------------
// Kernel 1: fold the 4 candidate ops into one combined matrix/bias.
//   Wc[f][d] = sum_o weights[o] * W[o][f][d]   (stored bf16)
//   bc[f]    = sum_o weights[o] * b[o][f]      (stored fp32)
// ---------------------------------------------------------------------------
__global__ void combine_kernel(const float* __restrict__ W,
                               const float* __restrict__ b,
                               const float* __restrict__ wts,
                               __hip_bfloat16* __restrict__ Wc,
                               float* __restrict__ bc) {
    int idx = blockIdx.x * blockDim.x + threadIdx.x;
    float w0 = wts[0], w1 = wts[1], w2 = wts[2], w3 = wts[3];
    if (idx < D * D) {
        float v = w0 * W[idx] + w1 * W[D * D + idx]
                + w2 * W[2 * D * D + idx] + w3 * W[3 * D * D + idx];
        Wc[idx] = __float2bfloat16(v);
    }
    if (idx < D) {
        bc[idx] = w0 * b[idx] + w1 * b[D + idx] + w2 * b[2 * D + idx] + w3 * b[3 * D + idx];
    }
}

// ---------------------------------------------------------------------------
// Kernel 2: y[m][f] = sum_d x[m][d] * Wc[f][d] + bc[f]   (M = B*S = 131072)
//
// Occupancy-first restructure: 512 threads = 8 waves = 4 row-slabs x 2
// col-halves. Each wave: 16 rows x 64 cols -> acc[4] (16 VGPR) + xf[4]
// (16 VGPR); persistent state ~60 VGPR => 8 waves/SIMD = 32 waves/CU
// (was 16). TLP does the latency hiding; code stays simple.
//
// A-frag = Wc (LDS, padded), B-frag = x => D[f][m]: lane holds 4
// consecutive y columns -> one dwordx4 NT store per 16-col tile.
// x loads are plain cached loads (R1's NT loads double-fetched the
// 32B-stride a0/a1 pattern -> +HBM fetch; reverted).
// ---------------------------------------------------------------------------
__device__ inline short8 cvt8_bf16(float4_t a, float4_t b) {
    union { short8 s; __hip_bfloat16 h[8]; } u;
    u.h[0] = __float2bfloat16(a[0]);
    u.h[1] = __float2bfloat16(a[1]);
    u.h[2] = __float2bfloat16(a[2]);
    u.h[3] = __float2bfloat16(a[3]);
    u.h[4] = __float2bfloat16(b[0]);
    u.h[5] = __float2bfloat16(b[1]);
    u.h[6] = __float2bfloat16(b[2]);
    u.h[7] = __float2bfloat16(b[3]);
    return u.s;
}

__global__ __launch_bounds__(512, 8) void gemm_kernel(const float* __restrict__ x,
                                                      const __hip_bfloat16* __restrict__ Wc,
                                                      const float* __restrict__ bc,
                                                      float* __restrict__ y,
                                                      int M) {
    __shared__ __align__(16) __hip_bfloat16 Bs[D * BS_STRIDE];  // 34816 B

    const int tid   = threadIdx.x;
    const int lane  = tid & 63;
    const int wave  = tid >> 6;
    const int wslab = wave >> 1;  // row-slab 0..3
    const int whalf = wave & 1;   // column half 0..1

    // ---- stage Wc -> LDS (2048 chunks of 8 bf16; 512 threads, 4 iters) ----
    #pragma unroll
    for (int i = 0; i < 4; i++) {
        int c  = i * 512 + tid;      // 0..2047
        int n  = c >> 4;             // row (0..127)
        int ko = (c & 15) << 3;      // k offset (0,8,...,120)
        short8 v = *(const short8*)((const short*)Wc + n * D + ko);
        *(short8*)((short*)Bs + n * BS_STRIDE + ko) = v;
    }
    __syncthreads();

    const int row  = lane & 15;   // A: f within tile / B: m within tile
    const int quad = lane >> 4;

    const int mbase = blockIdx.x * ROWS_PER_BLOCK + wslab * 16 + row;
    if (mbase >= M) return;

    // lane-constant LDS base; all 16 reads = base + compile-time immediate
    const short* bp0 = (const short*)Bs + (whalf * 64 + row) * BS_STRIDE + quad * 8;

    #pragma unroll
    for (int s = 0; s < 2; s++) {
        const int m = mbase + s * 64;  // this lane's x/y row

        // ---- x loads: 8 x dwordx4, plain cached (NOT nontemporal) ----
        const float* xp = x + (size_t)m * D + quad * 8;
        short8 xf[4];
        #pragma unroll
        for (int ks = 0; ks < 4; ks++) {
            float4_t a0 = *(const float4_t*)(xp + ks * 32);
            float4_t a1 = *(const float4_t*)(xp + ks * 32 + 4);
            xf[ks] = cvt8_bf16(a0, a1);
        }

        float4_t acc[4];
        #pragma unroll
        for (int i = 0; i < 4; i++) acc[i] = (float4_t)(0.f);

        // ---- MFMA: A = Wc[f][k] (LDS), B = x^T[k][m] -> D[f][m] ----
        #pragma unroll
        for (int ks = 0; ks < 4; ks++) {
            #pragma unroll
            for (int f = 0; f < 4; f++) {
                // A frag: Wc[(whalf*64 + f*16 + row)][ks*32 + quad*8 + j]
                short8 wfrag = *(const short8*)(bp0 + f * 16 * BS_STRIDE + ks * 32);
                acc[f] = __builtin_amdgcn_mfma_f32_16x16x32_bf16(wfrag, xf[ks], acc[f], 0, 0, 0);
            }
        }

        // ---- epilogue: lane holds y[m][whalf*64 + f*16 + quad*4 .. +3] ----
        float* yp = y + (size_t)m * D + whalf * 64 + quad * 4;
        #pragma unroll
        for (int f = 0; f < 4; f++) {
            float4_t bias = *(const float4_t*)(bc + whalf * 64 + f * 16 + quad * 4);
            float4_t out;
            out[0] = acc[f][0] + bias[0];
            out[1] = acc[f][1] + bias[1];
            out[2] = acc[f][2] + bias[2];
            out[3] = acc[f][3] + bias[3];
            __builtin_nontemporal_store(out, (float4_t*)(yp + f * 16));
        }
    }
}

extern "C" void kernel_launch(void* const* d_in, const int* in_sizes, int n_in,
                              void* d_out, int out_size, void* d_ws, size_t ws_size,
                              hipStream_t stream) {
    const float* x   = (const float*)d_in[0];   // (B,S,D) fp32
    const float* W   = (const float*)d_in[1];   // (NOPS,D,D) fp32
    const float* b   = (const float*)d_in[2];   // (NOPS,D) fp32
    const float* wts = (const float*)d_in[3];   // (NOPS,) fp32
    float* y = (float*)d_out;

    __hip_bfloat16* Wc = (__hip_bfloat16*)d_ws;
    float* bc = (float*)((char*)d_ws + D * D * sizeof(__hip_bfloat16));

    combine_kernel<<<(D * D + 255) / 256, 256, 0, stream>>>(W, b, wts, Wc, bc);

    const int M = in_sizes[0] / D;  // B*S = 131072
    gemm_kernel<<<M / ROWS_PER_BLOCK, 512, 0, stream>>>(x, Wc, bc, y, M);
}